// Round 12
// baseline (182.710 us; speedup 1.0000x reference)
//
#include <hip/hip_runtime.h>
#include <hip/hip_bf16.h>

// B=2, N=2048, E=1024, H=16, HD=64. Inputs fp32, output fp32.
// ws (32 MiB): kbuf qbuf vbuf sabuf (bf16, 8 MB each).
// Scratch plan (R12 = R11 + out_mfma N-split):
//   wqkv_t (6 MB)  -> sabuf bytes [0,6M), dead after qkv_mfma
//   wout_t (2 MB)  -> sabuf bytes [6M,8M), written by prep, read by out_mfma
//   ml     (1 MB)  -> sabuf bytes [0,1M), written by attn2 (wqkv_t dead)
//   xbf    (8 MB)  -> d_out[0..8M),  dead after qkv_mfma
//   vtb    (8 MB)  -> d_out[8..16M), written by transpose_v, dead after attn2
//   p0     (8 MB)  -> d_out[0..8M)  (attn2 partial 0, dead after merge)
//   p1     (8 MB)  -> vbuf          (partial 1; merge overwrites in place)
// 6 kernels: prep | qkv_mfma | transpose_v | attn2 | attn_merge | out_mfma.
// R12: out_mfma tile 128x64 -> 128x32, grid (32,32)=1024 = 4 blocks/CU
// (was 2, grid-capped). out_mfma stages SYNCHRONOUSLY (global->reg->ds_write)
// so TLP pays here, unlike qkv's async global_load_lds (R10 null).
// Same per-acc MFMA order -> bitwise-identical output.
// R10 lesson: qkv 128x96@4blk/CU neutral (K=1024 shallow + async staging).
// R6/R7/R8 lesson: do NOT fuse V^T into qkv (+17us both variants).
// NOTE: Q is written PRE-SCALED by 0.125*log2(e) in qkv epilogue; attn2's
// softmax runs in the log2 domain with no per-element scale.
#define Bz 2
#define Nn 2048
#define Ee 1024
#define Hh 16
#define HD 64

typedef unsigned short u16;
typedef unsigned int u32;

typedef __bf16 bf16x8 __attribute__((ext_vector_type(8)));
typedef float f32x4 __attribute__((ext_vector_type(4)));
typedef unsigned int u32x2 __attribute__((ext_vector_type(2)));

#define QK_SCALE 0.18033688f  // 0.125 * log2(e)

__device__ __forceinline__ float bf2f(u16 u) {
    u32 v = ((u32)u) << 16;
    return __builtin_bit_cast(float, v);
}
__device__ __forceinline__ u16 f2bf(float f) {
    u32 i = __builtin_bit_cast(u32, f);
    u32 r = (i + 0x7FFFu + ((i >> 16) & 1u)) >> 16;  // RNE
    return (u16)r;
}
__device__ __forceinline__ u32 pack2(float a, float b) {
    return (u32)f2bf(a) | ((u32)f2bf(b) << 16);
}
__device__ __forceinline__ bf16x8 ld_frag(const u16* p) {
    return __builtin_bit_cast(bf16x8, *(const uint4*)p);
}
__device__ __forceinline__ f32x4 zero4() {
    f32x4 z; z[0]=0.f; z[1]=0.f; z[2]=0.f; z[3]=0.f; return z;
}

// --- gfx950 cross-lane / pack primitives (T12) -----------------------------
// v_cvt_pk_bf16_f32: lo = bf16(a), hi = bf16(b). 1 VALU op vs ~5 for manual.
// Output-only "=v" (no tied-operand aliasing hazard).
__device__ __forceinline__ u32 cvt_pk_bf16(float a, float b) {
    u32 r;
    asm("v_cvt_pk_bf16_f32 %0, %1, %2" : "=v"(r) : "v"(a), "v"(b));
    return r;
}
// permlane swaps via BUILTINS (inline-asm "+v","+v" with identical inputs can
// be register-coalesced by regalloc -> same VGPR -> garbage; builtins return
// both results and let the compiler insert copies).
// pl32(a,b): r0 = [a.lo32, b.lo32], r1 = [a.hi32, b.hi32]
__device__ __forceinline__ u32x2 pl32(u32 a, u32 b) {
    return __builtin_amdgcn_permlane32_swap(a, b, false, false);
}
// pl16(a,b): r0 = [a.g0, b.g0, a.g2, b.g2], r1 = [a.g1, b.g1, a.g3, b.g3]
__device__ __forceinline__ u32x2 pl16(u32 a, u32 b) {
    return __builtin_amdgcn_permlane16_swap(a, b, false, false);
}
// full cross-quad (lane^16, lane^32) max/sum without ds_bpermute
__device__ __forceinline__ float qred_max(float x) {
    u32 xu = __builtin_bit_cast(u32, x);
    u32x2 r1 = pl16(xu, xu);   // r1[0]=x[i], r1[1]=x[i^16]
    float m = fmaxf(__builtin_bit_cast(float, (u32)r1[0]),
                    __builtin_bit_cast(float, (u32)r1[1]));
    u32 mu = __builtin_bit_cast(u32, m);
    u32x2 r2 = pl32(mu, mu);   // r2[0]=m[i], r2[1]=m[i^32]
    return fmaxf(__builtin_bit_cast(float, (u32)r2[0]),
                 __builtin_bit_cast(float, (u32)r2[1]));
}
__device__ __forceinline__ float qred_sum(float x) {
    u32 xu = __builtin_bit_cast(u32, x);
    u32x2 r1 = pl16(xu, xu);
    float m = __builtin_bit_cast(float, (u32)r1[0]) +
              __builtin_bit_cast(float, (u32)r1[1]);
    u32 mu = __builtin_bit_cast(u32, m);
    u32x2 r2 = pl32(mu, mu);
    return __builtin_bit_cast(float, (u32)r2[0]) +
           __builtin_bit_cast(float, (u32)r2[1]);
}

// async 16B/lane global->LDS DMA; LDS dest = (uniform base) + lane*16.
__device__ __forceinline__ void async_copy16(const u16* g, u16* l) {
    __builtin_amdgcn_global_load_lds(
        (const __attribute__((address_space(1))) u32*)g,
        (__attribute__((address_space(3))) u32*)l, 16, 0, 0);
}

__global__ void ws_diag(float* out, float code) { out[0] = code; }

// ---------------------------------------------------------------------------
// Prep (fused): convert_x (blocks 0..2047) | Wqkv f32->bf16 transpose
// (blocks 2048..2815, orig grid 16x3x16) | Wout transpose (2816..3071,
// orig grid 16x16). One static LDS tile shared by both transpose paths.
// ---------------------------------------------------------------------------
__device__ __forceinline__ void tr_f32_bf16(
    const float* __restrict__ src, u16* __restrict__ dst,
    int R, int C, int bx, int by, size_t zoff, int tid)
{
    __shared__ float T[64][65];
    const int r0 = bx * 64, c0 = by * 64;
    src += zoff; dst += zoff;
    {
        int tr = tid >> 2, tc = (tid & 3) * 16;
        const float* s = src + (size_t)(r0 + tr) * C + c0 + tc;
#pragma unroll
        for (int j = 0; j < 4; ++j) {
            float4 v = ((const float4*)s)[j];
            T[tr][tc + 4 * j + 0] = v.x; T[tr][tc + 4 * j + 1] = v.y;
            T[tr][tc + 4 * j + 2] = v.z; T[tr][tc + 4 * j + 3] = v.w;
        }
    }
    __syncthreads();
    {
        int cc = tid >> 2, rr = (tid & 3) * 16;
        u16* d = dst + (size_t)(c0 + cc) * R + r0 + rr;
        u32 w[8];
#pragma unroll
        for (int i = 0; i < 8; ++i)
            w[i] = pack2(T[rr + 2 * i][cc], T[rr + 2 * i + 1][cc]);
        *(uint4*)(d)     = make_uint4(w[0], w[1], w[2], w[3]);
        *(uint4*)(d + 8) = make_uint4(w[4], w[5], w[6], w[7]);
    }
}

__global__ __launch_bounds__(256) void prep(
    const float* __restrict__ x, u16* __restrict__ xbf,
    const float* __restrict__ Wqkv, u16* __restrict__ wqkv_t,
    const float* __restrict__ Wout, u16* __restrict__ wout_t)
{
    const int bid = blockIdx.x;
    const int tid = threadIdx.x;
    if (bid < 2048) {
        size_t idx = ((size_t)bid * 256 + tid) * 8;
        float4 f0 = *(const float4*)(x + idx);
        float4 f1 = *(const float4*)(x + idx + 4);
        uint4 pk;
        pk.x = pack2(f0.x, f0.y); pk.y = pack2(f0.z, f0.w);
        pk.z = pack2(f1.x, f1.y); pk.w = pack2(f1.z, f1.w);
        *(uint4*)(xbf + idx) = pk;
    } else if (bid < 2816) {
        // Wqkv: R=1024, C=192, 16 z-slices; orig dim3(16,3,16), lin = x+16y+48z
        int b2 = bid - 2048;
        tr_f32_bf16(Wqkv, wqkv_t, 1024, 192,
                    b2 & 15, (b2 >> 4) % 3,
                    (size_t)(b2 / 48) * 1024 * 192, tid);
    } else {
        // Wout: R=C=1024, single slice; orig dim3(16,16,1)
        int b3 = bid - 2816;
        tr_f32_bf16(Wout, wout_t, 1024, 1024, b3 & 15, b3 >> 4, 0, tid);
    }
}

// ---------------------------------------------------------------------------
// Transpose bf16 [2048 n][64 d] -> [64 d][2048 n] per bh slice (V -> V^T).
// (R5-proven: V^T fused into qkv's epilogue cost +17us in both R6-scatter
//  and R8-LDS variants; the separate kernel is ~3.5us.)
// ---------------------------------------------------------------------------
__global__ __launch_bounds__(256) void transpose_v(
    const u16* __restrict__ src, u16* __restrict__ dst)
{
    const int n0 = blockIdx.x * 64;
    const size_t z = blockIdx.y;
    src += z * (size_t)Nn * HD;
    dst += z * (size_t)HD * Nn;
    const int tid = threadIdx.x;

    __shared__ u16 T[64][66];
    {
        int tr = tid >> 2, tc = (tid & 3) * 16;
        const u16* s = src + (size_t)(n0 + tr) * HD + tc;
        *(uint4*)&T[tr][tc]     = *(const uint4*)(s);
        *(uint4*)&T[tr][tc + 8] = *(const uint4*)(s + 8);
    }
    __syncthreads();
    {
        int cc = tid >> 2, rr = (tid & 3) * 16;
        u32 w[8];
#pragma unroll
        for (int i = 0; i < 8; ++i)
            w[i] = (u32)T[rr + 2 * i][cc] | ((u32)T[rr + 2 * i + 1][cc] << 16);
        u16* d = dst + (size_t)cc * Nn + n0 + rr;
        *(uint4*)(d)     = make_uint4(w[0], w[1], w[2], w[3]);
        *(uint4*)(d + 8) = make_uint4(w[4], w[5], w[6], w[7]);
    }
}

// ---------------------------------------------------------------------------
// Kernel 1 v3 (R9-exact, measured-best): QKV projection, MFMA 16x16x32.
// Block 128m x 192n (one head), grid (32,16)=512. 4 waves 2x2, wave 64x96
// (4x6 frags -> 48 MFMA per k64 iter). LDS 40 KB unpadded, XOR chunk swizzle.
// R10's 128x96@4blk/CU split was neutral/worse (K=1024 too shallow).
// Q output pre-scaled by QK_SCALE. V stored straight to vbuf[bh][n][d].
// ---------------------------------------------------------------------------
__global__ __launch_bounds__(256) void qkv_mfma(
    const u16* __restrict__ xbf, const u16* __restrict__ Wt,
    const float* __restrict__ bias,
    u16* __restrict__ kbuf, u16* __restrict__ qbuf, u16* __restrict__ vbuf)
{
    const int mt = blockIdx.x;   // 0..31
    const int h  = blockIdx.y;   // 0..15
    const int tid = threadIdx.x;
    const int lane = tid & 63, wid = tid >> 6;
    const int wy = wid >> 1, wx = wid & 1;
    const int quad = lane >> 4, l15 = lane & 15;

    __shared__ u16 As[128 * 64];   // [m][8 chunks of 8], swizzled
    __shared__ u16 Bs[192 * 64];   // [n][8 chunks], swizzled

    f32x4 acc[4][6];
#pragma unroll
    for (int mi = 0; mi < 4; ++mi)
#pragma unroll
        for (int ni = 0; ni < 6; ++ni) acc[mi][ni] = zero4();

    const u16* xb = xbf + (size_t)mt * 128 * Ee;
    const u16* wtb = Wt + (size_t)h * 192 * 1024;

    const int arowl = lane >> 3;
    const int jj = (lane & 7) ^ arowl;

    for (int kb = 0; kb < 16; ++kb) {
        __syncthreads();  // prev-iter frag reads done
        // A: 128x64 = 16 KB = 16 insts, 4 per wave
#pragma unroll
        for (int i = 0; i < 4; ++i) {
            int rbase = (wid * 4 + i) * 8;
            const u16* g = xb + (size_t)(rbase + arowl) * Ee + kb * 64 + jj * 8;
            async_copy16(g, &As[(wid * 4 + i) * 512]);
        }
        // B: 192x64 = 24 KB = 24 insts, 6 per wave
#pragma unroll
        for (int i = 0; i < 6; ++i) {
            int rbase = (wid * 6 + i) * 8;
            const u16* g = wtb + (size_t)(rbase + arowl) * 1024 + kb * 64 + jj * 8;
            async_copy16(g, &Bs[(wid * 6 + i) * 512]);
        }
        __syncthreads();  // drains vmcnt before barrier

#pragma unroll
        for (int kk0 = 0; kk0 < 2; ++kk0) {
            const int pos = ((kk0 * 4 + quad) ^ (l15 & 7)) * 8;
            bf16x8 af[4], bf[6];
#pragma unroll
            for (int mi = 0; mi < 4; ++mi)
                af[mi] = ld_frag(&As[(wy * 64 + mi * 16 + l15) * 64 + pos]);
#pragma unroll
            for (int ni = 0; ni < 6; ++ni)
                bf[ni] = ld_frag(&Bs[(wx * 96 + ni * 16 + l15) * 64 + pos]);
#pragma unroll
            for (int mi = 0; mi < 4; ++mi)
#pragma unroll
                for (int ni = 0; ni < 6; ++ni)
                    acc[mi][ni] = __builtin_amdgcn_mfma_f32_16x16x32_bf16(
                        af[mi], bf[ni], acc[mi][ni], 0, 0, 0);
        }
    }

    // epilogue: C layout col=l15, row=quad*4+r. cols 0..191 = k|q|v.
    // Q (ft==1) is pre-scaled by QK_SCALE.
#pragma unroll
    for (int ni = 0; ni < 6; ++ni) {
        int col = wx * 96 + ni * 16 + l15;   // 0..191
        int ft = col >> 6, d = col & 63;
        u16* dst = (ft == 0) ? kbuf : (ft == 1) ? qbuf : vbuf;
        float sc = (ft == 1) ? QK_SCALE : 1.0f;
        float bv = bias[h * 192 + col];
#pragma unroll
        for (int mi = 0; mi < 4; ++mi)
#pragma unroll
            for (int r = 0; r < 4; ++r) {
                int gm = mt * 128 + wy * 64 + mi * 16 + quad * 4 + r;
                int bb = gm >> 11, n = gm & (Nn - 1);
                dst[(((size_t)(bb * Hh + h)) * Nn + n) * HD + d] =
                    f2bf((acc[mi][ni][r] + bv) * sc);
            }
    }
}

// ---------------------------------------------------------------------------
// Kernel 2 v11: split-K causal flash attention. INNER LOOP FROZEN (R3/R4:
// restructures produced nondeterministic corruption). sg on blockIdx.y,
// grid (1024,2), 2048 half-size blocks, 5 blocks/CU (32KB LDS).
// ---------------------------------------------------------------------------
__global__ __launch_bounds__(256, 4) void attn2(
    const u16* __restrict__ qbuf, const u16* __restrict__ kbuf,
    const u16* __restrict__ vtb, u16* __restrict__ p0buf,
    u16* __restrict__ p1buf, float* __restrict__ ml)
{
    const int id = blockIdx.x;                      // 0..1023
    const int sg = blockIdx.y;                      // 0..1 (was serial loop)
    const int bh = (id & 7) * 4 + ((id >> 3) & 3);  // 4 bh per XCD
    const int p  = id >> 5;                         // 0..31
    const int tid = threadIdx.x;
    const int lane = tid & 63, wid = tid >> 6;
    const int l15 = lane & 15, quad = lane >> 4;

    __shared__ u16 KsL[2][4096];   // [buf][key 64][d 64] chunk-swizzled
    __shared__ u16 VtL[2][4096];   // [buf][d 64][key 64] chunk-swizzled

    const u16* qb = qbuf + (size_t)bh * Nn * HD;
    const u16* kb = kbuf + (size_t)bh * Nn * HD;
    const u16* vt = vtb + (size_t)bh * HD * Nn;

    const int r_l = lane >> 3;
    const int jj = (lane & 7) ^ r_l;
    const int xsw = l15 & 7;

    const int qt = sg ? (31 - p) : p;
    const int T  = qt + 1;
    const int t0 = sg ? ((T + 1) >> 1) : 0;
    const int t1 = sg ? T : ((p + 2) >> 1);
    u16*   pb = sg ? p1buf : p0buf;
    float* mb = ml + (sg ? 131072 : 0);
    float* lb = ml + (sg ? 196608 : 65536);

    const int qrow = qt * 64 + wid * 16 + l15;

    f32x4 oacc[4];
#pragma unroll
    for (int dt = 0; dt < 4; ++dt) oacc[dt] = zero4();
    float m_i = -3e38f, l_i = 0.f;

    if (t0 < t1) {
        bf16x8 qf[2];
#pragma unroll
        for (int st = 0; st < 2; ++st)
            qf[st] = __builtin_bit_cast(bf16x8,
                *(const uint4*)(qb + (size_t)qrow * HD + st * 32 + quad * 8));

#pragma unroll
        for (int i2 = 0; i2 < 4; ++i2) {
            int idx = wid * 4 + i2;
            if (idx < 8) {
                const u16* g = kb + (size_t)(t0 * 64 + idx * 8 + r_l) * HD + jj * 8;
                async_copy16(g, &KsL[0][idx * 512]);
            } else {
                int ii = idx - 8;
                const u16* g = vt + (size_t)(ii * 8 + r_l) * Nn + t0 * 64 + jj * 8;
                async_copy16(g, &VtL[0][ii * 512]);
            }
        }

        const int nit = t1 - t0;
        for (int i = 0; i < nit; ++i) {
            const int tk = t0 + i;
            __syncthreads();  // drains DMA for buf[i&1]; fences prev reads
            if (i + 1 < nit) {
                const int nb = (i + 1) & 1;
#pragma unroll
                for (int i2 = 0; i2 < 4; ++i2) {
                    int idx = wid * 4 + i2;
                    if (idx < 8) {
                        const u16* g = kb + (size_t)((tk + 1) * 64 + idx * 8 + r_l) * HD + jj * 8;
                        async_copy16(g, &KsL[nb][idx * 512]);
                    } else {
                        int ii = idx - 8;
                        const u16* g = vt + (size_t)(ii * 8 + r_l) * Nn + (tk + 1) * 64 + jj * 8;
                        async_copy16(g, &VtL[nb][ii * 512]);
                    }
                }
            }
            const u16* K = KsL[i & 1];
            const u16* V = VtL[i & 1];

            // S^T[key][q] (already log2-scaled via Q)
            f32x4 s[4];
#pragma unroll
            for (int t = 0; t < 4; ++t) {
                f32x4 a = zero4();
#pragma unroll
                for (int st = 0; st < 2; ++st) {
                    bf16x8 kf = ld_frag(&K[(t * 16 + l15) * 64 +
                                           ((st * 4 + quad) ^ xsw) * 8]);
                    a = __builtin_amdgcn_mfma_f32_16x16x32_bf16(kf, qf[st], a, 0, 0, 0);
                }
                s[t] = a;
            }

            // causal mask only on the diagonal tile
            if (tk == qt) {
#pragma unroll
                for (int t = 0; t < 4; ++t)
#pragma unroll
                    for (int r = 0; r < 4; ++r) {
                        int key = tk * 64 + t * 16 + quad * 4 + r;
                        if (key > qrow) s[t][r] = -3e38f;
                    }
            }

            // online softmax (log2 domain), deferred-max rescale
            float mx = s[0][0];
#pragma unroll
            for (int t = 0; t < 4; ++t)
#pragma unroll
                for (int r = 0; r < 4; ++r) mx = fmaxf(mx, s[t][r]);
            mx = qred_max(mx);
            if (!__all(mx <= m_i + 8.0f)) {
                float mn = fmaxf(m_i, mx);
                float alpha = __builtin_amdgcn_exp2f(m_i - mn);
                m_i = mn;
                l_i *= alpha;
#pragma unroll
                for (int dt = 0; dt < 4; ++dt)
#pragma unroll
                    for (int r = 0; r < 4; ++r) oacc[dt][r] *= alpha;
            }
            float rs = 0.f;
#pragma unroll
            for (int t = 0; t < 4; ++t)
#pragma unroll
                for (int r = 0; r < 4; ++r) {
                    float e = __builtin_amdgcn_exp2f(s[t][r] - m_i);
                    s[t][r] = e;
                    rs += e;
                }
            l_i += qred_sum(rs);

            // pack P to bf16 pairs (single-op cvt_pk), then permlane
            // redistribution into B-operand fragments
            u32 pk[4][2];
#pragma unroll
            for (int t = 0; t < 4; ++t) {
                pk[t][0] = cvt_pk_bf16(s[t][0], s[t][1]);
                pk[t][1] = cvt_pk_bf16(s[t][2], s[t][3]);
            }
#pragma unroll
            for (int st = 0; st < 2; ++st) {
                u32x2 s0 = pl32(pk[2 * st][0], pk[2 * st + 1][0]);
                u32x2 u02 = pl16((u32)s0[0], (u32)s0[1]);  // [0]=U0, [1]=U2
                u32x2 s1 = pl32(pk[2 * st][1], pk[2 * st + 1][1]);
                u32x2 u13 = pl16((u32)s1[0], (u32)s1[1]);  // [0]=U1, [1]=U3
                bf16x8 pf = __builtin_bit_cast(bf16x8,
                    make_uint4((u32)u02[0], (u32)u13[0], (u32)u02[1], (u32)u13[1]));
#pragma unroll
                for (int dt = 0; dt < 4; ++dt) {
                    bf16x8 vf = ld_frag(&V[(dt * 16 + l15) * 64 +
                                           ((st * 4 + quad) ^ xsw) * 8]);
                    oacc[dt] = __builtin_amdgcn_mfma_f32_16x16x32_bf16(
                        vf, pf, oacc[dt], 0, 0, 0);
                }
            }
        }
    }

    // epilogue: UNNORMALIZED partial O' (bf16), layout [bh][n][d]
#pragma unroll
    for (int dt = 0; dt < 4; ++dt) {
        ushort4 ov;
        ov.x = f2bf(oacc[dt][0]);
        ov.y = f2bf(oacc[dt][1]);
        ov.z = f2bf(oacc[dt][2]);
        ov.w = f2bf(oacc[dt][3]);
        *(ushort4*)&pb[((size_t)bh * Nn + qrow) * HD + dt * 16 + quad * 4] = ov;
    }
    if (quad == 0) {
        mb[bh * Nn + qrow] = m_i;
        lb[bh * Nn + qrow] = l_i;
    }
}

// ---------------------------------------------------------------------------
// Merge: sa = (a1*p0 + a2*p1) / (a1*l1 + a2*l2); writes in place over p1.
// (Not fused into out_mfma: p0 lives in d_out, which out_mfma overwrites ->
//  cross-block RAW race. Kept as its own kernel.)
// ---------------------------------------------------------------------------
__global__ __launch_bounds__(256) void attn_merge(
    const u16* __restrict__ p0, u16* __restrict__ p1,
    const float* __restrict__ ml)
{
    const int idx = blockIdx.x * 256 + threadIdx.x;  // 0..524287
    const int row = idx >> 3;                        // bh*2048+n
    const int dc = (idx & 7) * 8;

    const float m1 = ml[row],          l1 = ml[65536 + row];
    const float m2 = ml[131072 + row], l2 = ml[196608 + row];
    const float m = fmaxf(m1, m2);
    const float a1 = exp2f(m1 - m), a2 = exp2f(m2 - m);
    const float inv = 1.f / (a1 * l1 + a2 * l2);
    const float s1 = a1 * inv, s2 = a2 * inv;

    const size_t off = (size_t)row * HD + dc;
    uint4 v0 = *(const uint4*)&p0[off];
    uint4 v1 = *(const uint4*)&p1[off];
    u32 a[4] = {v0.x, v0.y, v0.z, v0.w};
    u32 b[4] = {v1.x, v1.y, v1.z, v1.w};
    u32 w[4];
#pragma unroll
    for (int j = 0; j < 4; ++j) {
        float x0 = bf2f((u16)a[j]) * s1 + bf2f((u16)b[j]) * s2;
        float x1 = bf2f((u16)(a[j] >> 16)) * s1 + bf2f((u16)(b[j] >> 16)) * s2;
        w[j] = pack2(x0, x1);
    }
    *(uint4*)&p1[off] = make_uint4(w[0], w[1], w[2], w[3]);
}

// ---------------------------------------------------------------------------
// Kernel 3 v2: output projection, MFMA 32x32x16. A in [bh][n][d] layout.
// R12: tile 128m x 32n (was 128x64), grid (32,32)=1024 = 4 blocks/CU (was 2,
// grid-capped). Sync staging is latency-exposed -> TLP pays. One f32x16 acc
// per wave; same kc-order per acc -> bitwise-identical output.
// ---------------------------------------------------------------------------
typedef float f32x16 __attribute__((ext_vector_type(16)));
__device__ __forceinline__ f32x16 zero16() {
    f32x16 z;
#pragma unroll
    for (int i = 0; i < 16; ++i) z[i] = 0.f;
    return z;
}

__global__ __launch_bounds__(256) void out_mfma(
    const u16* __restrict__ A, const u16* __restrict__ Wt,
    const float* __restrict__ bias, float* __restrict__ out)
{
    const int mt = blockIdx.x;  // 0..31
    const int nt = blockIdx.y;  // 0..31
    const int tid = threadIdx.x;
    const int lane = tid & 63, wid = tid >> 6;
    const int l31 = lane & 31, khalf = (lane >> 5) * 8;

    __shared__ u16 As[128][72];
    __shared__ u16 Bs[32][72];

    f32x16 acc = zero16();

    const int arow = tid >> 1, akh = (tid & 1) * 32;
    const int gm = mt * 128 + arow;
    const int bb = gm >> 11, n = gm & (Nn - 1);
    const int brow = tid >> 3, bc = (tid & 7) * 8;   // 32 rows x 64 cols

    for (int k0 = 0; k0 < Ee; k0 += 64) {
        __syncthreads();
        {
            const int c = k0 + akh;
            const int h = c >> 6, d0 = c & 63;
            const u16* asrc = A + (((size_t)(bb * Hh + h) * Nn + n) * HD + d0);
#pragma unroll
            for (int j = 0; j < 4; ++j)
                *(uint4*)&As[arow][akh + 8 * j] = *(const uint4*)(asrc + 8 * j);
            const u16* bsrc = Wt + (size_t)(nt * 32 + brow) * 1024 + k0 + bc;
            *(uint4*)&Bs[brow][bc] = *(const uint4*)(bsrc);
        }
        __syncthreads();
#pragma unroll
        for (int kc = 0; kc < 4; ++kc) {
            bf16x8 af = ld_frag(&As[wid * 32 + l31][kc * 16 + khalf]);
            bf16x8 bf = ld_frag(&Bs[l31][kc * 16 + khalf]);
            acc = __builtin_amdgcn_mfma_f32_32x32x16_bf16(af, bf, acc, 0, 0, 0);
        }
    }

    {
        int col = nt * 32 + l31;
        float bv = bias[col];
#pragma unroll
        for (int r = 0; r < 16; ++r) {
            int row_l = (r & 3) + 8 * (r >> 2) + 4 * (lane >> 5);
            int gm2 = mt * 128 + wid * 32 + row_l;
            out[(size_t)gm2 * Ee + col] = acc[r] + bv;
        }
    }
}

// ---------------------------------------------------------------------------
extern "C" void kernel_launch(void* const* d_in, const int* in_sizes, int n_in,
                              void* d_out, int out_size, void* d_ws, size_t ws_size,
                              hipStream_t stream) {
    const float* x    = (const float*)d_in[0];  // [2,2048,1024] f32
    const float* Wqkv = (const float*)d_in[1];  // [16,1024,192] f32
    const float* bqkv = (const float*)d_in[2];  // [16,192] f32
    const float* Wout = (const float*)d_in[3];  // [1024,1024] f32
    const float* bout = (const float*)d_in[4];  // [1024] f32
    float* out = (float*)d_out;                 // [2,2048,1024] f32

    const size_t SZ = (size_t)Bz * Hh * Nn * HD;        // 4,194,304 elems
    const size_t NSA = (size_t)Bz * Nn * Ee;            // 4,194,304 elems
    const size_t NEED = (3 * SZ + NSA) * sizeof(u16);   // 32 MiB

    if (ws_size < NEED) {
        ws_diag<<<1, 1, 0, stream>>>(out, 20000.0f + (float)(ws_size >> 20));
        return;
    }

    u16* ws = (u16*)d_ws;
    u16* kbuf  = ws;
    u16* qbuf  = ws + SZ;
    u16* vbuf  = ws + 2 * SZ;
    u16* sabuf = ws + 3 * SZ;
    u16* wqkv_t = sabuf;                       // 6 MB (dead after qkv_mfma)
    u16* wout_t = sabuf + 3 * 1024 * 1024;     // 2 MB, sabuf bytes [6M,8M)
    u16* xbf    = (u16*)d_out;                 // 8 MB scratch (dead after qkv)
    u16* vtb    = (u16*)d_out + SZ;            // 8 MB V^T (dead after attn2)
    u16* p0     = (u16*)d_out;                 // partial 0 (reuses xbf region)
    u16* p1     = vbuf;                        // partial 1; merge -> final sa
    float* ml   = (float*)sabuf;               // 1 MB (wqkv_t dead by then)

    prep<<<3072, 256, 0, stream>>>(x, xbf, Wqkv, wqkv_t, Wout, wout_t);
    qkv_mfma<<<dim3(32, 16), 256, 0, stream>>>(xbf, wqkv_t, bqkv, kbuf, qbuf, vbuf);
    transpose_v<<<dim3(32, 32), 256, 0, stream>>>(vbuf, vtb);
    attn2<<<dim3(1024, 2), 256, 0, stream>>>(qbuf, kbuf, vtb, p0, p1, ml);
    attn_merge<<<dim3(2048), 256, 0, stream>>>(p0, p1, ml);
    out_mfma<<<dim3(32, 32), 256, 0, stream>>>(p1, wout_t, bout, out);
}

// Round 13
// 170.133 us; speedup vs baseline: 1.0739x; 1.0739x over previous
//
#include <hip/hip_runtime.h>
#include <hip/hip_bf16.h>

// B=2, N=2048, E=1024, H=16, HD=64. Inputs fp32, output fp32.
// ws (32 MiB): kbuf qbuf vbuf sabuf (bf16, 8 MB each).
// Scratch plan (R13 = R11 exact, the measured-best 170.9us config):
//   wqkv_t (6 MB)  -> sabuf bytes [0,6M), dead after qkv_mfma
//   wout_t (2 MB)  -> sabuf bytes [6M,8M), written by prep, read by out_mfma
//   ml     (1 MB)  -> sabuf bytes [0,1M), written by attn2 (wqkv_t dead)
//   xbf    (8 MB)  -> d_out[0..8M),  dead after qkv_mfma
//   vtb    (8 MB)  -> d_out[8..16M), written by transpose_v, dead after attn2
//   p0     (8 MB)  -> d_out[0..8M)  (attn2 partial 0, dead after merge)
//   p1     (8 MB)  -> vbuf          (partial 1; merge overwrites in place)
// 6 kernels: prep | qkv_mfma | transpose_v | attn2 | attn_merge | out_mfma.
// Session ledger (dur_us): 197.0 base -> 184.3 (permlane softmax) -> 183.7
// (attn2 launch_bounds(256,4)) -> 177.6 (fused prep) -> 170.9 (attn2 sg-split).
// Dead ends, do not revisit without counter-level cause:
//  - V^T fused into qkv: +17us BOTH variants (R6 scatter, R8 LDS; R7 showed
//    barrier-after-global-store drains vmcnt(0) = +20us stall).
//  - Tile-narrowing for occupancy on shallow-K GEMMs: R10 qkv neutral,
//    R12 out_mfma -12us (halves compute:staging ratio, doubles A traffic).
//  - attn2/qkv inner-loop restructures: R3/R4 nondeterministic corruption.
//  - merge->out_mfma fusion: cross-block RAW race (p0 aliases d_out).
// NOTE: Q is written PRE-SCALED by 0.125*log2(e) in qkv epilogue; attn2's
// softmax runs in the log2 domain with no per-element scale.
#define Bz 2
#define Nn 2048
#define Ee 1024
#define Hh 16
#define HD 64

typedef unsigned short u16;
typedef unsigned int u32;

typedef __bf16 bf16x8 __attribute__((ext_vector_type(8)));
typedef float f32x4 __attribute__((ext_vector_type(4)));
typedef unsigned int u32x2 __attribute__((ext_vector_type(2)));

#define QK_SCALE 0.18033688f  // 0.125 * log2(e)

__device__ __forceinline__ float bf2f(u16 u) {
    u32 v = ((u32)u) << 16;
    return __builtin_bit_cast(float, v);
}
__device__ __forceinline__ u16 f2bf(float f) {
    u32 i = __builtin_bit_cast(u32, f);
    u32 r = (i + 0x7FFFu + ((i >> 16) & 1u)) >> 16;  // RNE
    return (u16)r;
}
__device__ __forceinline__ u32 pack2(float a, float b) {
    return (u32)f2bf(a) | ((u32)f2bf(b) << 16);
}
__device__ __forceinline__ bf16x8 ld_frag(const u16* p) {
    return __builtin_bit_cast(bf16x8, *(const uint4*)p);
}
__device__ __forceinline__ f32x4 zero4() {
    f32x4 z; z[0]=0.f; z[1]=0.f; z[2]=0.f; z[3]=0.f; return z;
}

// --- gfx950 cross-lane / pack primitives (T12) -----------------------------
// v_cvt_pk_bf16_f32: lo = bf16(a), hi = bf16(b). 1 VALU op vs ~5 for manual.
// Output-only "=v" (no tied-operand aliasing hazard).
__device__ __forceinline__ u32 cvt_pk_bf16(float a, float b) {
    u32 r;
    asm("v_cvt_pk_bf16_f32 %0, %1, %2" : "=v"(r) : "v"(a), "v"(b));
    return r;
}
// permlane swaps via BUILTINS (inline-asm "+v","+v" with identical inputs can
// be register-coalesced by regalloc -> same VGPR -> garbage; builtins return
// both results and let the compiler insert copies).
// pl32(a,b): r0 = [a.lo32, b.lo32], r1 = [a.hi32, b.hi32]
__device__ __forceinline__ u32x2 pl32(u32 a, u32 b) {
    return __builtin_amdgcn_permlane32_swap(a, b, false, false);
}
// pl16(a,b): r0 = [a.g0, b.g0, a.g2, b.g2], r1 = [a.g1, b.g1, a.g3, b.g3]
__device__ __forceinline__ u32x2 pl16(u32 a, u32 b) {
    return __builtin_amdgcn_permlane16_swap(a, b, false, false);
}
// full cross-quad (lane^16, lane^32) max/sum without ds_bpermute
__device__ __forceinline__ float qred_max(float x) {
    u32 xu = __builtin_bit_cast(u32, x);
    u32x2 r1 = pl16(xu, xu);   // r1[0]=x[i], r1[1]=x[i^16]
    float m = fmaxf(__builtin_bit_cast(float, (u32)r1[0]),
                    __builtin_bit_cast(float, (u32)r1[1]));
    u32 mu = __builtin_bit_cast(u32, m);
    u32x2 r2 = pl32(mu, mu);   // r2[0]=m[i], r2[1]=m[i^32]
    return fmaxf(__builtin_bit_cast(float, (u32)r2[0]),
                 __builtin_bit_cast(float, (u32)r2[1]));
}
__device__ __forceinline__ float qred_sum(float x) {
    u32 xu = __builtin_bit_cast(u32, x);
    u32x2 r1 = pl16(xu, xu);
    float m = __builtin_bit_cast(float, (u32)r1[0]) +
              __builtin_bit_cast(float, (u32)r1[1]);
    u32 mu = __builtin_bit_cast(u32, m);
    u32x2 r2 = pl32(mu, mu);
    return __builtin_bit_cast(float, (u32)r2[0]) +
           __builtin_bit_cast(float, (u32)r2[1]);
}

// async 16B/lane global->LDS DMA; LDS dest = (uniform base) + lane*16.
__device__ __forceinline__ void async_copy16(const u16* g, u16* l) {
    __builtin_amdgcn_global_load_lds(
        (const __attribute__((address_space(1))) u32*)g,
        (__attribute__((address_space(3))) u32*)l, 16, 0, 0);
}

__global__ void ws_diag(float* out, float code) { out[0] = code; }

// ---------------------------------------------------------------------------
// Prep (fused): convert_x (blocks 0..2047) | Wqkv f32->bf16 transpose
// (blocks 2048..2815, orig grid 16x3x16) | Wout transpose (2816..3071,
// orig grid 16x16). One static LDS tile shared by both transpose paths.
// ---------------------------------------------------------------------------
__device__ __forceinline__ void tr_f32_bf16(
    const float* __restrict__ src, u16* __restrict__ dst,
    int R, int C, int bx, int by, size_t zoff, int tid)
{
    __shared__ float T[64][65];
    const int r0 = bx * 64, c0 = by * 64;
    src += zoff; dst += zoff;
    {
        int tr = tid >> 2, tc = (tid & 3) * 16;
        const float* s = src + (size_t)(r0 + tr) * C + c0 + tc;
#pragma unroll
        for (int j = 0; j < 4; ++j) {
            float4 v = ((const float4*)s)[j];
            T[tr][tc + 4 * j + 0] = v.x; T[tr][tc + 4 * j + 1] = v.y;
            T[tr][tc + 4 * j + 2] = v.z; T[tr][tc + 4 * j + 3] = v.w;
        }
    }
    __syncthreads();
    {
        int cc = tid >> 2, rr = (tid & 3) * 16;
        u16* d = dst + (size_t)(c0 + cc) * R + r0 + rr;
        u32 w[8];
#pragma unroll
        for (int i = 0; i < 8; ++i)
            w[i] = pack2(T[rr + 2 * i][cc], T[rr + 2 * i + 1][cc]);
        *(uint4*)(d)     = make_uint4(w[0], w[1], w[2], w[3]);
        *(uint4*)(d + 8) = make_uint4(w[4], w[5], w[6], w[7]);
    }
}

__global__ __launch_bounds__(256) void prep(
    const float* __restrict__ x, u16* __restrict__ xbf,
    const float* __restrict__ Wqkv, u16* __restrict__ wqkv_t,
    const float* __restrict__ Wout, u16* __restrict__ wout_t)
{
    const int bid = blockIdx.x;
    const int tid = threadIdx.x;
    if (bid < 2048) {
        size_t idx = ((size_t)bid * 256 + tid) * 8;
        float4 f0 = *(const float4*)(x + idx);
        float4 f1 = *(const float4*)(x + idx + 4);
        uint4 pk;
        pk.x = pack2(f0.x, f0.y); pk.y = pack2(f0.z, f0.w);
        pk.z = pack2(f1.x, f1.y); pk.w = pack2(f1.z, f1.w);
        *(uint4*)(xbf + idx) = pk;
    } else if (bid < 2816) {
        // Wqkv: R=1024, C=192, 16 z-slices; orig dim3(16,3,16), lin = x+16y+48z
        int b2 = bid - 2048;
        tr_f32_bf16(Wqkv, wqkv_t, 1024, 192,
                    b2 & 15, (b2 >> 4) % 3,
                    (size_t)(b2 / 48) * 1024 * 192, tid);
    } else {
        // Wout: R=C=1024, single slice; orig dim3(16,16,1)
        int b3 = bid - 2816;
        tr_f32_bf16(Wout, wout_t, 1024, 1024, b3 & 15, b3 >> 4, 0, tid);
    }
}

// ---------------------------------------------------------------------------
// Transpose bf16 [2048 n][64 d] -> [64 d][2048 n] per bh slice (V -> V^T).
// (R5-proven: V^T fused into qkv's epilogue cost +17us in both R6-scatter
//  and R8-LDS variants; the separate kernel is ~3.5us.)
// ---------------------------------------------------------------------------
__global__ __launch_bounds__(256) void transpose_v(
    const u16* __restrict__ src, u16* __restrict__ dst)
{
    const int n0 = blockIdx.x * 64;
    const size_t z = blockIdx.y;
    src += z * (size_t)Nn * HD;
    dst += z * (size_t)HD * Nn;
    const int tid = threadIdx.x;

    __shared__ u16 T[64][66];
    {
        int tr = tid >> 2, tc = (tid & 3) * 16;
        const u16* s = src + (size_t)(n0 + tr) * HD + tc;
        *(uint4*)&T[tr][tc]     = *(const uint4*)(s);
        *(uint4*)&T[tr][tc + 8] = *(const uint4*)(s + 8);
    }
    __syncthreads();
    {
        int cc = tid >> 2, rr = (tid & 3) * 16;
        u32 w[8];
#pragma unroll
        for (int i = 0; i < 8; ++i)
            w[i] = (u32)T[rr + 2 * i][cc] | ((u32)T[rr + 2 * i + 1][cc] << 16);
        u16* d = dst + (size_t)cc * Nn + n0 + rr;
        *(uint4*)(d)     = make_uint4(w[0], w[1], w[2], w[3]);
        *(uint4*)(d + 8) = make_uint4(w[4], w[5], w[6], w[7]);
    }
}

// ---------------------------------------------------------------------------
// Kernel 1 v3 (R9-exact, measured-best): QKV projection, MFMA 16x16x32.
// Block 128m x 192n (one head), grid (32,16)=512. 4 waves 2x2, wave 64x96
// (4x6 frags -> 48 MFMA per k64 iter). LDS 40 KB unpadded, XOR chunk swizzle.
// Q output pre-scaled by QK_SCALE. V stored straight to vbuf[bh][n][d].
// ---------------------------------------------------------------------------
__global__ __launch_bounds__(256) void qkv_mfma(
    const u16* __restrict__ xbf, const u16* __restrict__ Wt,
    const float* __restrict__ bias,
    u16* __restrict__ kbuf, u16* __restrict__ qbuf, u16* __restrict__ vbuf)
{
    const int mt = blockIdx.x;   // 0..31
    const int h  = blockIdx.y;   // 0..15
    const int tid = threadIdx.x;
    const int lane = tid & 63, wid = tid >> 6;
    const int wy = wid >> 1, wx = wid & 1;
    const int quad = lane >> 4, l15 = lane & 15;

    __shared__ u16 As[128 * 64];   // [m][8 chunks of 8], swizzled
    __shared__ u16 Bs[192 * 64];   // [n][8 chunks], swizzled

    f32x4 acc[4][6];
#pragma unroll
    for (int mi = 0; mi < 4; ++mi)
#pragma unroll
        for (int ni = 0; ni < 6; ++ni) acc[mi][ni] = zero4();

    const u16* xb = xbf + (size_t)mt * 128 * Ee;
    const u16* wtb = Wt + (size_t)h * 192 * 1024;

    const int arowl = lane >> 3;
    const int jj = (lane & 7) ^ arowl;

    for (int kb = 0; kb < 16; ++kb) {
        __syncthreads();  // prev-iter frag reads done
        // A: 128x64 = 16 KB = 16 insts, 4 per wave
#pragma unroll
        for (int i = 0; i < 4; ++i) {
            int rbase = (wid * 4 + i) * 8;
            const u16* g = xb + (size_t)(rbase + arowl) * Ee + kb * 64 + jj * 8;
            async_copy16(g, &As[(wid * 4 + i) * 512]);
        }
        // B: 192x64 = 24 KB = 24 insts, 6 per wave
#pragma unroll
        for (int i = 0; i < 6; ++i) {
            int rbase = (wid * 6 + i) * 8;
            const u16* g = wtb + (size_t)(rbase + arowl) * 1024 + kb * 64 + jj * 8;
            async_copy16(g, &Bs[(wid * 6 + i) * 512]);
        }
        __syncthreads();  // drains vmcnt before barrier

#pragma unroll
        for (int kk0 = 0; kk0 < 2; ++kk0) {
            const int pos = ((kk0 * 4 + quad) ^ (l15 & 7)) * 8;
            bf16x8 af[4], bf[6];
#pragma unroll
            for (int mi = 0; mi < 4; ++mi)
                af[mi] = ld_frag(&As[(wy * 64 + mi * 16 + l15) * 64 + pos]);
#pragma unroll
            for (int ni = 0; ni < 6; ++ni)
                bf[ni] = ld_frag(&Bs[(wx * 96 + ni * 16 + l15) * 64 + pos]);
#pragma unroll
            for (int mi = 0; mi < 4; ++mi)
#pragma unroll
                for (int ni = 0; ni < 6; ++ni)
                    acc[mi][ni] = __builtin_amdgcn_mfma_f32_16x16x32_bf16(
                        af[mi], bf[ni], acc[mi][ni], 0, 0, 0);
        }
    }

    // epilogue: C layout col=l15, row=quad*4+r. cols 0..191 = k|q|v.
    // Q (ft==1) is pre-scaled by QK_SCALE.
#pragma unroll
    for (int ni = 0; ni < 6; ++ni) {
        int col = wx * 96 + ni * 16 + l15;   // 0..191
        int ft = col >> 6, d = col & 63;
        u16* dst = (ft == 0) ? kbuf : (ft == 1) ? qbuf : vbuf;
        float sc = (ft == 1) ? QK_SCALE : 1.0f;
        float bv = bias[h * 192 + col];
#pragma unroll
        for (int mi = 0; mi < 4; ++mi)
#pragma unroll
            for (int r = 0; r < 4; ++r) {
                int gm = mt * 128 + wy * 64 + mi * 16 + quad * 4 + r;
                int bb = gm >> 11, n = gm & (Nn - 1);
                dst[(((size_t)(bb * Hh + h)) * Nn + n) * HD + d] =
                    f2bf((acc[mi][ni][r] + bv) * sc);
            }
    }
}

// ---------------------------------------------------------------------------
// Kernel 2 v11: split-K causal flash attention. INNER LOOP FROZEN (R3/R4:
// restructures produced nondeterministic corruption). sg on blockIdx.y,
// grid (1024,2), 2048 half-size blocks, 5 blocks/CU (32KB LDS).
// ---------------------------------------------------------------------------
__global__ __launch_bounds__(256, 4) void attn2(
    const u16* __restrict__ qbuf, const u16* __restrict__ kbuf,
    const u16* __restrict__ vtb, u16* __restrict__ p0buf,
    u16* __restrict__ p1buf, float* __restrict__ ml)
{
    const int id = blockIdx.x;                      // 0..1023
    const int sg = blockIdx.y;                      // 0..1 (was serial loop)
    const int bh = (id & 7) * 4 + ((id >> 3) & 3);  // 4 bh per XCD
    const int p  = id >> 5;                         // 0..31
    const int tid = threadIdx.x;
    const int lane = tid & 63, wid = tid >> 6;
    const int l15 = lane & 15, quad = lane >> 4;

    __shared__ u16 KsL[2][4096];   // [buf][key 64][d 64] chunk-swizzled
    __shared__ u16 VtL[2][4096];   // [buf][d 64][key 64] chunk-swizzled

    const u16* qb = qbuf + (size_t)bh * Nn * HD;
    const u16* kb = kbuf + (size_t)bh * Nn * HD;
    const u16* vt = vtb + (size_t)bh * HD * Nn;

    const int r_l = lane >> 3;
    const int jj = (lane & 7) ^ r_l;
    const int xsw = l15 & 7;

    const int qt = sg ? (31 - p) : p;
    const int T  = qt + 1;
    const int t0 = sg ? ((T + 1) >> 1) : 0;
    const int t1 = sg ? T : ((p + 2) >> 1);
    u16*   pb = sg ? p1buf : p0buf;
    float* mb = ml + (sg ? 131072 : 0);
    float* lb = ml + (sg ? 196608 : 65536);

    const int qrow = qt * 64 + wid * 16 + l15;

    f32x4 oacc[4];
#pragma unroll
    for (int dt = 0; dt < 4; ++dt) oacc[dt] = zero4();
    float m_i = -3e38f, l_i = 0.f;

    if (t0 < t1) {
        bf16x8 qf[2];
#pragma unroll
        for (int st = 0; st < 2; ++st)
            qf[st] = __builtin_bit_cast(bf16x8,
                *(const uint4*)(qb + (size_t)qrow * HD + st * 32 + quad * 8));

#pragma unroll
        for (int i2 = 0; i2 < 4; ++i2) {
            int idx = wid * 4 + i2;
            if (idx < 8) {
                const u16* g = kb + (size_t)(t0 * 64 + idx * 8 + r_l) * HD + jj * 8;
                async_copy16(g, &KsL[0][idx * 512]);
            } else {
                int ii = idx - 8;
                const u16* g = vt + (size_t)(ii * 8 + r_l) * Nn + t0 * 64 + jj * 8;
                async_copy16(g, &VtL[0][ii * 512]);
            }
        }

        const int nit = t1 - t0;
        for (int i = 0; i < nit; ++i) {
            const int tk = t0 + i;
            __syncthreads();  // drains DMA for buf[i&1]; fences prev reads
            if (i + 1 < nit) {
                const int nb = (i + 1) & 1;
#pragma unroll
                for (int i2 = 0; i2 < 4; ++i2) {
                    int idx = wid * 4 + i2;
                    if (idx < 8) {
                        const u16* g = kb + (size_t)((tk + 1) * 64 + idx * 8 + r_l) * HD + jj * 8;
                        async_copy16(g, &KsL[nb][idx * 512]);
                    } else {
                        int ii = idx - 8;
                        const u16* g = vt + (size_t)(ii * 8 + r_l) * Nn + (tk + 1) * 64 + jj * 8;
                        async_copy16(g, &VtL[nb][ii * 512]);
                    }
                }
            }
            const u16* K = KsL[i & 1];
            const u16* V = VtL[i & 1];

            // S^T[key][q] (already log2-scaled via Q)
            f32x4 s[4];
#pragma unroll
            for (int t = 0; t < 4; ++t) {
                f32x4 a = zero4();
#pragma unroll
                for (int st = 0; st < 2; ++st) {
                    bf16x8 kf = ld_frag(&K[(t * 16 + l15) * 64 +
                                           ((st * 4 + quad) ^ xsw) * 8]);
                    a = __builtin_amdgcn_mfma_f32_16x16x32_bf16(kf, qf[st], a, 0, 0, 0);
                }
                s[t] = a;
            }

            // causal mask only on the diagonal tile
            if (tk == qt) {
#pragma unroll
                for (int t = 0; t < 4; ++t)
#pragma unroll
                    for (int r = 0; r < 4; ++r) {
                        int key = tk * 64 + t * 16 + quad * 4 + r;
                        if (key > qrow) s[t][r] = -3e38f;
                    }
            }

            // online softmax (log2 domain), deferred-max rescale
            float mx = s[0][0];
#pragma unroll
            for (int t = 0; t < 4; ++t)
#pragma unroll
                for (int r = 0; r < 4; ++r) mx = fmaxf(mx, s[t][r]);
            mx = qred_max(mx);
            if (!__all(mx <= m_i + 8.0f)) {
                float mn = fmaxf(m_i, mx);
                float alpha = __builtin_amdgcn_exp2f(m_i - mn);
                m_i = mn;
                l_i *= alpha;
#pragma unroll
                for (int dt = 0; dt < 4; ++dt)
#pragma unroll
                    for (int r = 0; r < 4; ++r) oacc[dt][r] *= alpha;
            }
            float rs = 0.f;
#pragma unroll
            for (int t = 0; t < 4; ++t)
#pragma unroll
                for (int r = 0; r < 4; ++r) {
                    float e = __builtin_amdgcn_exp2f(s[t][r] - m_i);
                    s[t][r] = e;
                    rs += e;
                }
            l_i += qred_sum(rs);

            // pack P to bf16 pairs (single-op cvt_pk), then permlane
            // redistribution into B-operand fragments
            u32 pk[4][2];
#pragma unroll
            for (int t = 0; t < 4; ++t) {
                pk[t][0] = cvt_pk_bf16(s[t][0], s[t][1]);
                pk[t][1] = cvt_pk_bf16(s[t][2], s[t][3]);
            }
#pragma unroll
            for (int st = 0; st < 2; ++st) {
                u32x2 s0 = pl32(pk[2 * st][0], pk[2 * st + 1][0]);
                u32x2 u02 = pl16((u32)s0[0], (u32)s0[1]);  // [0]=U0, [1]=U2
                u32x2 s1 = pl32(pk[2 * st][1], pk[2 * st + 1][1]);
                u32x2 u13 = pl16((u32)s1[0], (u32)s1[1]);  // [0]=U1, [1]=U3
                bf16x8 pf = __builtin_bit_cast(bf16x8,
                    make_uint4((u32)u02[0], (u32)u13[0], (u32)u02[1], (u32)u13[1]));
#pragma unroll
                for (int dt = 0; dt < 4; ++dt) {
                    bf16x8 vf = ld_frag(&V[(dt * 16 + l15) * 64 +
                                           ((st * 4 + quad) ^ xsw) * 8]);
                    oacc[dt] = __builtin_amdgcn_mfma_f32_16x16x32_bf16(
                        vf, pf, oacc[dt], 0, 0, 0);
                }
            }
        }
    }

    // epilogue: UNNORMALIZED partial O' (bf16), layout [bh][n][d]
#pragma unroll
    for (int dt = 0; dt < 4; ++dt) {
        ushort4 ov;
        ov.x = f2bf(oacc[dt][0]);
        ov.y = f2bf(oacc[dt][1]);
        ov.z = f2bf(oacc[dt][2]);
        ov.w = f2bf(oacc[dt][3]);
        *(ushort4*)&pb[((size_t)bh * Nn + qrow) * HD + dt * 16 + quad * 4] = ov;
    }
    if (quad == 0) {
        mb[bh * Nn + qrow] = m_i;
        lb[bh * Nn + qrow] = l_i;
    }
}

// ---------------------------------------------------------------------------
// Merge: sa = (a1*p0 + a2*p1) / (a1*l1 + a2*l2); writes in place over p1.
// (Not fused into out_mfma: p0 lives in d_out, which out_mfma overwrites ->
//  cross-block RAW race. Kept as its own kernel.)
// ---------------------------------------------------------------------------
__global__ __launch_bounds__(256) void attn_merge(
    const u16* __restrict__ p0, u16* __restrict__ p1,
    const float* __restrict__ ml)
{
    const int idx = blockIdx.x * 256 + threadIdx.x;  // 0..524287
    const int row = idx >> 3;                        // bh*2048+n
    const int dc = (idx & 7) * 8;

    const float m1 = ml[row],          l1 = ml[65536 + row];
    const float m2 = ml[131072 + row], l2 = ml[196608 + row];
    const float m = fmaxf(m1, m2);
    const float a1 = exp2f(m1 - m), a2 = exp2f(m2 - m);
    const float inv = 1.f / (a1 * l1 + a2 * l2);
    const float s1 = a1 * inv, s2 = a2 * inv;

    const size_t off = (size_t)row * HD + dc;
    uint4 v0 = *(const uint4*)&p0[off];
    uint4 v1 = *(const uint4*)&p1[off];
    u32 a[4] = {v0.x, v0.y, v0.z, v0.w};
    u32 b[4] = {v1.x, v1.y, v1.z, v1.w};
    u32 w[4];
#pragma unroll
    for (int j = 0; j < 4; ++j) {
        float x0 = bf2f((u16)a[j]) * s1 + bf2f((u16)b[j]) * s2;
        float x1 = bf2f((u16)(a[j] >> 16)) * s1 + bf2f((u16)(b[j] >> 16)) * s2;
        w[j] = pack2(x0, x1);
    }
    *(uint4*)&p1[off] = make_uint4(w[0], w[1], w[2], w[3]);
}

// ---------------------------------------------------------------------------
// Kernel 3 (R11-exact, measured-best): output projection, MFMA 32x32x16.
// Tile 128x64, grid (32,16)=512. R12's 128x32@4blk/CU split regressed -12us
// (halved compute:staging ratio, doubled A traffic) -> reverted.
// ---------------------------------------------------------------------------
typedef float f32x16 __attribute__((ext_vector_type(16)));
__device__ __forceinline__ f32x16 zero16() {
    f32x16 z;
#pragma unroll
    for (int i = 0; i < 16; ++i) z[i] = 0.f;
    return z;
}

__global__ __launch_bounds__(256) void out_mfma(
    const u16* __restrict__ A, const u16* __restrict__ Wt,
    const float* __restrict__ bias, float* __restrict__ out)
{
    const int mt = blockIdx.x;  // 0..31
    const int nt = blockIdx.y;  // 0..15
    const int tid = threadIdx.x;
    const int lane = tid & 63, wid = tid >> 6;
    const int l31 = lane & 31, khalf = (lane >> 5) * 8;

    __shared__ u16 As[128][72];
    __shared__ u16 Bs[64][72];

    f32x16 acc[2];
    acc[0] = zero16(); acc[1] = zero16();

    const int arow = tid >> 1, akh = (tid & 1) * 32;
    const int gm = mt * 128 + arow;
    const int bb = gm >> 11, n = gm & (Nn - 1);
    const int brow = tid >> 2, bc = (tid & 3) * 16;

    for (int k0 = 0; k0 < Ee; k0 += 64) {
        __syncthreads();
        {
            const int c = k0 + akh;
            const int h = c >> 6, d0 = c & 63;
            const u16* asrc = A + (((size_t)(bb * Hh + h) * Nn + n) * HD + d0);
#pragma unroll
            for (int j = 0; j < 4; ++j)
                *(uint4*)&As[arow][akh + 8 * j] = *(const uint4*)(asrc + 8 * j);
            const u16* bsrc = Wt + (size_t)(nt * 64 + brow) * 1024 + k0 + bc;
            *(uint4*)&Bs[brow][bc]     = *(const uint4*)(bsrc);
            *(uint4*)&Bs[brow][bc + 8] = *(const uint4*)(bsrc + 8);
        }
        __syncthreads();
#pragma unroll
        for (int kc = 0; kc < 4; ++kc) {
            bf16x8 af = ld_frag(&As[wid * 32 + l31][kc * 16 + khalf]);
#pragma unroll
            for (int ct = 0; ct < 2; ++ct) {
                bf16x8 bf = ld_frag(&Bs[ct * 32 + l31][kc * 16 + khalf]);
                acc[ct] = __builtin_amdgcn_mfma_f32_32x32x16_bf16(af, bf, acc[ct], 0, 0, 0);
            }
        }
    }

#pragma unroll
    for (int ct = 0; ct < 2; ++ct) {
        int col = nt * 64 + ct * 32 + l31;
        float bv = bias[col];
#pragma unroll
        for (int r = 0; r < 16; ++r) {
            int row_l = (r & 3) + 8 * (r >> 2) + 4 * (lane >> 5);
            int gm2 = mt * 128 + wid * 32 + row_l;
            out[(size_t)gm2 * Ee + col] = acc[ct][r] + bv;
        }
    }
}

// ---------------------------------------------------------------------------
extern "C" void kernel_launch(void* const* d_in, const int* in_sizes, int n_in,
                              void* d_out, int out_size, void* d_ws, size_t ws_size,
                              hipStream_t stream) {
    const float* x    = (const float*)d_in[0];  // [2,2048,1024] f32
    const float* Wqkv = (const float*)d_in[1];  // [16,1024,192] f32
    const float* bqkv = (const float*)d_in[2];  // [16,192] f32
    const float* Wout = (const float*)d_in[3];  // [1024,1024] f32
    const float* bout = (const float*)d_in[4];  // [1024] f32
    float* out = (float*)d_out;                 // [2,2048,1024] f32

    const size_t SZ = (size_t)Bz * Hh * Nn * HD;        // 4,194,304 elems
    const size_t NSA = (size_t)Bz * Nn * Ee;            // 4,194,304 elems
    const size_t NEED = (3 * SZ + NSA) * sizeof(u16);   // 32 MiB

    if (ws_size < NEED) {
        ws_diag<<<1, 1, 0, stream>>>(out, 20000.0f + (float)(ws_size >> 20));
        return;
    }

    u16* ws = (u16*)d_ws;
    u16* kbuf  = ws;
    u16* qbuf  = ws + SZ;
    u16* vbuf  = ws + 2 * SZ;
    u16* sabuf = ws + 3 * SZ;
    u16* wqkv_t = sabuf;                       // 6 MB (dead after qkv_mfma)
    u16* wout_t = sabuf + 3 * 1024 * 1024;     // 2 MB, sabuf bytes [6M,8M)
    u16* xbf    = (u16*)d_out;                 // 8 MB scratch (dead after qkv)
    u16* vtb    = (u16*)d_out + SZ;            // 8 MB V^T (dead after attn2)
    u16* p0     = (u16*)d_out;                 // partial 0 (reuses xbf region)
    u16* p1     = vbuf;                        // partial 1; merge -> final sa
    float* ml   = (float*)sabuf;               // 1 MB (wqkv_t dead by then)

    prep<<<3072, 256, 0, stream>>>(x, xbf, Wqkv, wqkv_t, Wout, wout_t);
    qkv_mfma<<<dim3(32, 16), 256, 0, stream>>>(xbf, wqkv_t, bqkv, kbuf, qbuf, vbuf);
    transpose_v<<<dim3(32, 32), 256, 0, stream>>>(vbuf, vtb);
    attn2<<<dim3(1024, 2), 256, 0, stream>>>(qbuf, kbuf, vtb, p0, p1, ml);
    attn_merge<<<dim3(2048), 256, 0, stream>>>(p0, p1, ml);
    out_mfma<<<dim3(32, 16), 256, 0, stream>>>(p1, wout_t, bout, out);
}